// Round 3
// baseline (1245.679 us; speedup 1.0000x reference)
//
#include <hip/hip_runtime.h>
#include <hip/hip_bf16.h>

#define NN 100000
#define IN_CH 128
#define HID 8
#define HEADS 8
#define HC 64  // HEADS*HID
#define BK_SH 7          // 128 nodes per bucket
#define NB ((NN + (1 << BK_SH) - 1) >> BK_SH)  // 782 buckets

__device__ __forceinline__ unsigned short f2bf(float f) {
    unsigned u = __float_as_uint(f);
    unsigned r = (u + 0x7fffu + ((u >> 16) & 1u)) >> 16;
    return (unsigned short)r;
}

// ---------------- CSR build ----------------

__global__ __launch_bounds__(256) void k_hist(const int* __restrict__ ei, int E, int ET,
                                              int* __restrict__ deg) {
    int t = blockIdx.x * 256 + threadIdx.x;
    if (t >= ET) return;
    int d = (t < E) ? ei[E + t] : (t - E);
    atomicAdd(&deg[d], 1);
}

__global__ __launch_bounds__(256) void k_scan_a(const int* __restrict__ deg, int n,
                                                int* __restrict__ csum) {
    __shared__ int sd[256];
    int t = threadIdx.x;
    int base = blockIdx.x * 2048;
    int s = 0;
#pragma unroll
    for (int i = 0; i < 8; ++i) {
        int gi = base + t * 8 + i;
        s += (gi < n) ? deg[gi] : 0;
    }
    sd[t] = s;
    __syncthreads();
    for (int off = 128; off > 0; off >>= 1) {
        if (t < off) sd[t] += sd[t + off];
        __syncthreads();
    }
    if (t == 0) csum[blockIdx.x] = sd[0];
}

__global__ void k_scan_b(int* csum, int nb) {
    if (threadIdx.x == 0) {
        int run = 0;
        for (int b = 0; b < nb; ++b) { int v = csum[b]; csum[b] = run; run += v; }
    }
}

__global__ __launch_bounds__(256) void k_scan_c(const int* __restrict__ deg, int n,
                                                const int* __restrict__ csum,
                                                int* __restrict__ row_ptr) {
    __shared__ int sd[256];
    int t = threadIdx.x;
    int base = blockIdx.x * 2048;
    int v[8];
    int tt = 0;
#pragma unroll
    for (int i = 0; i < 8; ++i) {
        int gi = base + t * 8 + i;
        v[i] = (gi < n) ? deg[gi] : 0;
        tt += v[i];
    }
    sd[t] = tt;
    __syncthreads();
    for (int off = 1; off < 256; off <<= 1) {
        int u = (t >= off) ? sd[t - off] : 0;
        __syncthreads();
        sd[t] += u;
        __syncthreads();
    }
    int excl = csum[blockIdx.x] + sd[t] - tt;
#pragma unroll
    for (int i = 0; i < 8; ++i) {
        int gi = base + t * 8 + i;
        if (gi < n) row_ptr[gi] = excl;
        if (gi == n - 1) row_ptr[n] = excl + v[i];
        excl += v[i];
    }
}

// Phase 1: bucket append (frontier writes stay L2-resident -> full-line writebacks)
__global__ __launch_bounds__(256) void k_bucket(const int* __restrict__ ei, int E, int ET,
                                                const int* __restrict__ row_ptr,
                                                int* __restrict__ bcur,
                                                int2* __restrict__ pairs) {
    int t = blockIdx.x * 256 + threadIdx.x;
    if (t >= ET) return;
    int s, d;
    if (t < E) { s = ei[t]; d = ei[E + t]; } else { s = t - E; d = t - E; }
    int b = d >> BK_SH;
    int base = row_ptr[b << BK_SH];
    int pos = atomicAdd(&bcur[b], 1);
    pairs[(size_t)base + pos] = make_int2(s, d);
}

// Phase 2: coalesced pair read, scatter within a ~17KB L2-resident window
__global__ __launch_bounds__(256) void k_scatter2(const int2* __restrict__ pairs, int ET,
                                                  const int* __restrict__ row_ptr,
                                                  int* __restrict__ cursor,
                                                  int* __restrict__ csr) {
    int t = blockIdx.x * 256 + threadIdx.x;
    if (t >= ET) return;
    int2 p = pairs[t];
    int pos = atomicAdd(&cursor[p.y], 1);
    csr[row_ptr[p.y] + pos] = p.x;
}

// ---------------- Layer 1: h1 = x@W1 (bf16 out), alpha_src/dst ----------------

__global__ __launch_bounds__(256) void k_gemm1(const float* __restrict__ x,
                                               const float* __restrict__ W1,
                                               const float* __restrict__ aS,
                                               const float* __restrict__ aD,
                                               unsigned short* __restrict__ h1bf,
                                               float* __restrict__ asrc1,
                                               float* __restrict__ adst1) {
    __shared__ float wl[IN_CH * HC];  // 32 KB
    int tid = threadIdx.x;
    {
        const float4* Wg4 = (const float4*)W1;
        float4* wl4 = (float4*)wl;
#pragma unroll
        for (int i = 0; i < 8; ++i) wl4[tid + i * 256] = Wg4[tid + i * 256];
    }
    __syncthreads();
    int lane = tid & 63;
    int row = blockIdx.x * 16 + (tid >> 6) * 4 + (lane >> 4);
    int c0 = (lane & 15) * 4;
    const float4* xr = (const float4*)(x + (size_t)row * IN_CH);
    float4 acc = make_float4(0.f, 0.f, 0.f, 0.f);
#pragma unroll 4
    for (int kq = 0; kq < IN_CH / 4; ++kq) {
        float4 xv = xr[kq];
        const float4* wrow = (const float4*)(wl + (kq * 4) * HC + c0);
        float4 w0 = wrow[0];
        float4 w1 = wrow[HC / 4];
        float4 w2 = wrow[2 * (HC / 4)];
        float4 w3 = wrow[3 * (HC / 4)];
        acc.x += xv.x * w0.x + xv.y * w1.x + xv.z * w2.x + xv.w * w3.x;
        acc.y += xv.x * w0.y + xv.y * w1.y + xv.z * w2.y + xv.w * w3.y;
        acc.z += xv.x * w0.z + xv.y * w1.z + xv.z * w2.z + xv.w * w3.z;
        acc.w += xv.x * w0.w + xv.y * w1.w + xv.z * w2.w + xv.w * w3.w;
    }
    ushort4 hb;
    hb.x = f2bf(acc.x); hb.y = f2bf(acc.y); hb.z = f2bf(acc.z); hb.w = f2bf(acc.w);
    *(ushort4*)(h1bf + (size_t)row * HC + c0) = hb;
    int head = (lane & 15) >> 1;
    int cl = c0 & 7;
    const float* as = aS + head * 8 + cl;
    const float* ad = aD + head * 8 + cl;
    float ps = acc.x * as[0] + acc.y * as[1] + acc.z * as[2] + acc.w * as[3];
    float pd = acc.x * ad[0] + acc.y * ad[1] + acc.z * ad[2] + acc.w * ad[3];
    ps += __shfl_xor(ps, 1, 64);
    pd += __shfl_xor(pd, 1, 64);
    if ((lane & 1) == 0) {
        asrc1[row * 8 + head] = ps;
        adst1[row * 8 + head] = pd;
    }
}

// ---------------- Layer 1 aggregation: one wave per node, 8 slots x 8 lanes,
// lane = head (8 bf16 channels), single-pass online softmax ----------------

__global__ __launch_bounds__(256) void k_agg1(const int* __restrict__ row_ptr,
                                              const int* __restrict__ csr,
                                              const float* __restrict__ asrc1,
                                              const float* __restrict__ adst1,
                                              const unsigned short* __restrict__ h1bf,
                                              const float* __restrict__ b1,
                                              float* __restrict__ hrelu) {
    int tid = threadIdx.x;
    int lane = tid & 63;
    int n = blockIdx.x * 4 + (tid >> 6);
    int slot = lane >> 3;  // 0..7 edge slot
    int hl = lane & 7;     // head
    float adst = adst1[n * 8 + hl];
    int beg = row_ptr[n], end = row_ptr[n + 1];
    int nit = (end - beg + 7) >> 3;
    float m = -3.0e38f, z = 0.f;
    float4 accA = make_float4(0.f, 0.f, 0.f, 0.f);
    float4 accB = make_float4(0.f, 0.f, 0.f, 0.f);
    const float4* h1v = (const float4*)h1bf;
    int j = beg + slot;
    int s_cur = (j < end) ? csr[j] : -1;
    for (int it = 0; it < nit; ++it) {
        int jn = j + 8;
        int s_nxt = (jn < end) ? csr[jn] : -1;
        if (s_cur >= 0) {
            float e = asrc1[s_cur * 8 + hl] + adst;
            e = (e > 0.f) ? e : 0.2f * e;
            float4 raw = h1v[(size_t)s_cur * 8 + hl];
            unsigned ux = __float_as_uint(raw.x), uy = __float_as_uint(raw.y);
            unsigned uz = __float_as_uint(raw.z), uw = __float_as_uint(raw.w);
            float v0 = __uint_as_float(ux << 16), v1 = __uint_as_float(ux & 0xffff0000u);
            float v2 = __uint_as_float(uy << 16), v3 = __uint_as_float(uy & 0xffff0000u);
            float v4 = __uint_as_float(uz << 16), v5 = __uint_as_float(uz & 0xffff0000u);
            float v6 = __uint_as_float(uw << 16), v7 = __uint_as_float(uw & 0xffff0000u);
            float mn = fmaxf(m, e);
            float rs = __expf(m - mn);
            float p = __expf(e - mn);
            m = mn;
            z = z * rs + p;
            accA.x = accA.x * rs + p * v0;
            accA.y = accA.y * rs + p * v1;
            accA.z = accA.z * rs + p * v2;
            accA.w = accA.w * rs + p * v3;
            accB.x = accB.x * rs + p * v4;
            accB.y = accB.y * rs + p * v5;
            accB.z = accB.z * rs + p * v6;
            accB.w = accB.w * rs + p * v7;
        }
        j = jn;
        s_cur = s_nxt;
    }
    // merge the 8 slots (partners at lane^8, ^16, ^32)
#pragma unroll
    for (int off = 8; off <= 32; off <<= 1) {
        float mo = __shfl_xor(m, off, 64);
        float zo = __shfl_xor(z, off, 64);
        float a0 = __shfl_xor(accA.x, off, 64);
        float a1 = __shfl_xor(accA.y, off, 64);
        float a2 = __shfl_xor(accA.z, off, 64);
        float a3 = __shfl_xor(accA.w, off, 64);
        float a4 = __shfl_xor(accB.x, off, 64);
        float a5 = __shfl_xor(accB.y, off, 64);
        float a6 = __shfl_xor(accB.z, off, 64);
        float a7 = __shfl_xor(accB.w, off, 64);
        float mn = fmaxf(m, mo);
        float rs = __expf(m - mn);
        float ro = __expf(mo - mn);
        m = mn;
        z = z * rs + zo * ro;
        accA.x = accA.x * rs + a0 * ro;
        accA.y = accA.y * rs + a1 * ro;
        accA.z = accA.z * rs + a2 * ro;
        accA.w = accA.w * rs + a3 * ro;
        accB.x = accB.x * rs + a4 * ro;
        accB.y = accB.y * rs + a5 * ro;
        accB.z = accB.z * rs + a6 * ro;
        accB.w = accB.w * rs + a7 * ro;
    }
    if (slot == 0) {
        float inv = 1.f / (z + 1e-16f);
        const float4* bv = (const float4*)(b1 + hl * 8);
        float4 b0 = bv[0], b1v = bv[1];
        float4 o0, o1;
        o0.x = fmaxf(accA.x * inv + b0.x, 0.f);
        o0.y = fmaxf(accA.y * inv + b0.y, 0.f);
        o0.z = fmaxf(accA.z * inv + b0.z, 0.f);
        o0.w = fmaxf(accA.w * inv + b0.w, 0.f);
        o1.x = fmaxf(accB.x * inv + b1v.x, 0.f);
        o1.y = fmaxf(accB.y * inv + b1v.y, 0.f);
        o1.z = fmaxf(accB.z * inv + b1v.z, 0.f);
        o1.w = fmaxf(accB.w * inv + b1v.w, 0.f);
        float4* op = (float4*)(hrelu + (size_t)n * HC + hl * 8);
        op[0] = o0;
        op[1] = o1;
    }
}

// ---------------- Layer 2: h2 = hrelu@W2, alpha2 ----------------

__global__ __launch_bounds__(256) void k_gemm2(const float* __restrict__ hrelu,
                                               const float* __restrict__ W2,
                                               const float* __restrict__ aS2,
                                               const float* __restrict__ aD2,
                                               float* __restrict__ h2,
                                               float* __restrict__ asrc2,
                                               float* __restrict__ adst2) {
    __shared__ float wl[HC * HID];  // 2 KB
    int tid = threadIdx.x;
    if (tid < 128) ((float4*)wl)[tid] = ((const float4*)W2)[tid];
    __syncthreads();
    int lane = tid & 63;
    int row = blockIdx.x * 32 + (tid >> 6) * 8 + (lane >> 3);
    int c = lane & 7;
    const float4* hr4 = (const float4*)(hrelu + (size_t)row * HC);
    float acc = 0.f;
#pragma unroll
    for (int kq = 0; kq < HC / 4; ++kq) {
        float4 hv = hr4[kq];
        acc += hv.x * wl[(kq * 4 + 0) * HID + c] + hv.y * wl[(kq * 4 + 1) * HID + c] +
               hv.z * wl[(kq * 4 + 2) * HID + c] + hv.w * wl[(kq * 4 + 3) * HID + c];
    }
    h2[(size_t)row * HID + c] = acc;
    float ps = acc * aS2[c];
    float pd = acc * aD2[c];
    ps += __shfl_xor(ps, 1, 64); ps += __shfl_xor(ps, 2, 64); ps += __shfl_xor(ps, 4, 64);
    pd += __shfl_xor(pd, 1, 64); pd += __shfl_xor(pd, 2, 64); pd += __shfl_xor(pd, 4, 64);
    if (c == 0) { asrc2[row] = ps; adst2[row] = pd; }
}

// ---------------- Layer 2 aggregation + classifier ----------------

__global__ __launch_bounds__(256) void k_agg2(const int* __restrict__ row_ptr,
                                              const int* __restrict__ csr,
                                              const float* __restrict__ asrc2,
                                              const float* __restrict__ adst2,
                                              const float* __restrict__ h2,
                                              const float* __restrict__ b2,
                                              const float* __restrict__ Wc,
                                              const float* __restrict__ bc,
                                              float* __restrict__ out) {
    int tid = threadIdx.x;
    int lane = tid & 63;
    int n = blockIdx.x * 4 + (tid >> 6);
    int slot = lane >> 3;
    int sl = lane & 7;
    float adst = adst2[n];
    int beg = row_ptr[n], end = row_ptr[n + 1];
    int nit = (end - beg + 7) >> 3;
    float m = -3.0e38f, z = 0.f, acc = 0.f;
    int j = beg + slot;
    int s_cur = (j < end) ? csr[j] : -1;
    for (int it = 0; it < nit; ++it) {
        int jn = j + 8;
        int s_nxt = (jn < end) ? csr[jn] : -1;
        if (s_cur >= 0) {
            float e = asrc2[s_cur] + adst;
            e = (e > 0.f) ? e : 0.2f * e;
            float hv = h2[(size_t)s_cur * HID + sl];
            float mn = fmaxf(m, e);
            float rs = __expf(m - mn);
            float p = __expf(e - mn);
            m = mn;
            z = z * rs + p;
            acc = acc * rs + p * hv;
        }
        j = jn;
        s_cur = s_nxt;
    }
#pragma unroll
    for (int off = 8; off <= 32; off <<= 1) {
        float mo = __shfl_xor(m, off, 64);
        float zo = __shfl_xor(z, off, 64);
        float ao = __shfl_xor(acc, off, 64);
        float mn = fmaxf(m, mo);
        float rs = __expf(m - mn);
        float ro = __expf(mo - mn);
        m = mn;
        z = z * rs + zo * ro;
        acc = acc * rs + ao * ro;
    }
    float emb = acc / (z + 1e-16f) + b2[sl];
    if (slot == 0) out[(size_t)n * HID + sl] = emb;
    float t0 = emb * Wc[sl * 2 + 0];
    float t1 = emb * Wc[sl * 2 + 1];
    t0 += __shfl_xor(t0, 1, 64); t0 += __shfl_xor(t0, 2, 64); t0 += __shfl_xor(t0, 4, 64);
    t1 += __shfl_xor(t1, 1, 64); t1 += __shfl_xor(t1, 2, 64); t1 += __shfl_xor(t1, 4, 64);
    if (lane == 0) {
        out[(size_t)NN * HID + n * 2 + 0] = t0 + bc[0];
        out[(size_t)NN * HID + n * 2 + 1] = t1 + bc[1];
    }
}

// ---------------- launch ----------------

extern "C" void kernel_launch(void* const* d_in, const int* in_sizes, int n_in,
                              void* d_out, int out_size, void* d_ws, size_t ws_size,
                              hipStream_t stream) {
    const float* x  = (const float*)d_in[0];
    const int*   ei = (const int*)d_in[1];
    const float* W1 = (const float*)d_in[2];
    const float* aS = (const float*)d_in[3];
    const float* aD = (const float*)d_in[4];
    const float* b1 = (const float*)d_in[5];
    const float* W2 = (const float*)d_in[6];
    const float* aS2 = (const float*)d_in[7];
    const float* aD2 = (const float*)d_in[8];
    const float* b2 = (const float*)d_in[9];
    const float* Wc = (const float*)d_in[10];
    const float* bc = (const float*)d_in[11];

    int E = in_sizes[1] / 2;
    int N = NN;
    int ET = E + N;

    char* p = (char*)d_ws;
    auto alloc = [&](size_t bytes) -> char* {
        char* r = p;
        p += (bytes + 255) & ~(size_t)255;
        return r;
    };
    unsigned short* h1bf = (unsigned short*)alloc((size_t)N * HC * 2);  // 12.8 MB
    float* hrelu  = (float*)alloc((size_t)N * HC * 4);                  // 25.6 MB
    float* asrc1  = (float*)alloc((size_t)N * 8 * 4);
    float* adst1  = (float*)alloc((size_t)N * 8 * 4);
    float* h2     = (float*)alloc((size_t)N * HID * 4);
    float* asrc2  = (float*)alloc((size_t)N * 4);
    float* adst2  = (float*)alloc((size_t)N * 4);
    int*   deg    = (int*)alloc((size_t)N * 4);
    int*   row_ptr= (int*)alloc((size_t)(N + 1) * 4);
    int*   cursor = (int*)alloc((size_t)N * 4);
    int*   csum   = (int*)alloc(256 * 4);
    int*   bcur   = (int*)alloc((size_t)NB * 4);
    int*   csr    = (int*)alloc((size_t)ET * 4);
    // pairs (26.4 MB) aliases h1bf+hrelu: dead before k_gemm1 writes them
    int2*  pairs  = (int2*)h1bf;

    hipMemsetAsync(deg, 0, (size_t)N * 4, stream);
    hipMemsetAsync(cursor, 0, (size_t)N * 4, stream);
    hipMemsetAsync(bcur, 0, (size_t)NB * 4, stream);

    int eb = (ET + 255) / 256;
    k_hist<<<eb, 256, 0, stream>>>(ei, E, ET, deg);
    int nch = (N + 2047) / 2048;
    k_scan_a<<<nch, 256, 0, stream>>>(deg, N, csum);
    k_scan_b<<<1, 64, 0, stream>>>(csum, nch);
    k_scan_c<<<nch, 256, 0, stream>>>(deg, N, csum, row_ptr);
    k_bucket<<<eb, 256, 0, stream>>>(ei, E, ET, row_ptr, bcur, pairs);
    k_scatter2<<<eb, 256, 0, stream>>>(pairs, ET, row_ptr, cursor, csr);

    k_gemm1<<<N / 16, 256, 0, stream>>>(x, W1, aS, aD, h1bf, asrc1, adst1);
    k_agg1<<<N / 4, 256, 0, stream>>>(row_ptr, csr, asrc1, adst1, h1bf, b1, hrelu);
    k_gemm2<<<N / 32, 256, 0, stream>>>(hrelu, W2, aS2, aD2, h2, asrc2, adst2);
    k_agg2<<<N / 4, 256, 0, stream>>>(row_ptr, csr, asrc2, adst2, h2, b2, Wc, bc,
                                      (float*)d_out);
}

// Round 4
// 275.049 us; speedup vs baseline: 4.5289x; 4.5289x over previous
//
#include <hip/hip_runtime.h>
#include <hip/hip_bf16.h>

#define NN 100000
#define IN_CH 128
#define HID 8
#define HEADS 8
#define HC 64   // HEADS*HID
#define BSH 8   // 256 nodes per bucket
#define NBUCK ((NN + 255) >> 8)   // 391
#define NBLK 512

__device__ __forceinline__ unsigned short f2bf(float f) {
    unsigned u = __float_as_uint(f);
    unsigned r = (u + 0x7fffu + ((u >> 16) & 1u)) >> 16;
    return (unsigned short)r;
}

// ---------------- CSR build: deterministic two-level binning ----------------

// K1: per-block LDS histogram over dst buckets
__global__ __launch_bounds__(256) void k_bincount(const int* __restrict__ ei, int E, int ET,
                                                  int cpb, int* __restrict__ cnt) {
    __shared__ int h[NBUCK];
    for (int i = threadIdx.x; i < NBUCK; i += 256) h[i] = 0;
    __syncthreads();
    int beg = blockIdx.x * cpb, end = min(ET, beg + cpb);
    for (int t = beg + threadIdx.x; t < end; t += 256) {
        int d = (t < E) ? ei[E + t] : (t - E);
        atomicAdd(&h[d >> BSH], 1);
    }
    __syncthreads();
    for (int i = threadIdx.x; i < NBUCK; i += 256) cnt[i * NBLK + blockIdx.x] = h[i];
}

// K2: per-bucket exclusive scan over the 512 block counts (in place), bucket total out
__global__ __launch_bounds__(256) void k_colscan(int* __restrict__ cnt, int* __restrict__ btot) {
    __shared__ int sd[256];
    int t = threadIdx.x;
    int* col = cnt + blockIdx.x * NBLK;
    int v0 = col[2 * t], v1 = col[2 * t + 1];
    int s = v0 + v1;
    sd[t] = s;
    __syncthreads();
    for (int off = 1; off < 256; off <<= 1) {
        int u = (t >= off) ? sd[t - off] : 0;
        __syncthreads();
        sd[t] += u;
        __syncthreads();
    }
    int excl = sd[t] - s;
    col[2 * t] = excl;
    col[2 * t + 1] = excl + v0;
    if (t == 255) btot[blockIdx.x] = excl + s;
}

// K3: exclusive scan over bucket totals -> bucket bases (+ row_ptr[N] sentinel)
__global__ __launch_bounds__(256) void k_bucketbase(const int* __restrict__ btot,
                                                    int* __restrict__ bbase,
                                                    int* __restrict__ row_ptr) {
    __shared__ int sd[256];
    int t = threadIdx.x;
    int v0 = (2 * t < NBUCK) ? btot[2 * t] : 0;
    int v1 = (2 * t + 1 < NBUCK) ? btot[2 * t + 1] : 0;
    int s = v0 + v1;
    sd[t] = s;
    __syncthreads();
    for (int off = 1; off < 256; off <<= 1) {
        int u = (t >= off) ? sd[t - off] : 0;
        __syncthreads();
        sd[t] += u;
        __syncthreads();
    }
    int excl = sd[t] - s;
    if (2 * t < NBUCK) bbase[2 * t] = excl;
    if (2 * t + 1 < NBUCK) bbase[2 * t + 1] = excl + v0;
    if (t == 255) { bbase[NBUCK] = excl + s; row_ptr[NN] = excl + s; }
}

// K4: replay with LDS cursors, append (src,dst) pairs into bucket-sorted order
__global__ __launch_bounds__(256) void k_binscatter(const int* __restrict__ ei, int E, int ET,
                                                    int cpb, const int* __restrict__ cnt,
                                                    const int* __restrict__ bbase,
                                                    int2* __restrict__ pairs) {
    __shared__ int cur[NBUCK];
    for (int i = threadIdx.x; i < NBUCK; i += 256)
        cur[i] = bbase[i] + cnt[i * NBLK + blockIdx.x];
    __syncthreads();
    int beg = blockIdx.x * cpb, end = min(ET, beg + cpb);
    for (int t = beg + threadIdx.x; t < end; t += 256) {
        int s, d;
        if (t < E) { s = ei[t]; d = ei[E + t]; } else { s = t - E; d = t - E; }
        int pos = atomicAdd(&cur[d >> BSH], 1);
        pairs[pos] = make_int2(s, d);
    }
}

// K5: one block per bucket — LDS node histogram -> row_ptr, then scatter src into
// the bucket's exclusive (single-XCD, L2-resident) csr window
__global__ __launch_bounds__(256) void k_bucketscatter(const int2* __restrict__ pairs,
                                                       const int* __restrict__ bbase,
                                                       int* __restrict__ row_ptr,
                                                       int* __restrict__ csr) {
    __shared__ int h[256];
    __shared__ int sd[256];
    int b = blockIdx.x;
    int t = threadIdx.x;
    int beg = bbase[b], end = bbase[b + 1];
    h[t] = 0;
    __syncthreads();
    for (int j = beg + t; j < end; j += 256) {
        int2 p = pairs[j];
        atomicAdd(&h[p.y & 255], 1);
    }
    __syncthreads();
    int v = h[t];
    sd[t] = v;
    __syncthreads();
    for (int off = 1; off < 256; off <<= 1) {
        int u = (t >= off) ? sd[t - off] : 0;
        __syncthreads();
        sd[t] += u;
        __syncthreads();
    }
    int excl = sd[t] - v;
    int node = (b << 8) + t;
    if (node < NN) row_ptr[node] = beg + excl;
    __syncthreads();
    h[t] = beg + excl;  // cursor
    __syncthreads();
    for (int j = beg + t; j < end; j += 256) {
        int2 p = pairs[j];
        int pos = atomicAdd(&h[p.y & 255], 1);
        csr[pos] = p.x;
    }
}

// ---------------- Layer 1: h1 = x@W1 (bf16 out), alpha_src/dst ----------------

__global__ __launch_bounds__(256) void k_gemm1(const float* __restrict__ x,
                                               const float* __restrict__ W1,
                                               const float* __restrict__ aS,
                                               const float* __restrict__ aD,
                                               unsigned short* __restrict__ h1bf,
                                               float* __restrict__ asrc1,
                                               float* __restrict__ adst1) {
    __shared__ float wl[IN_CH * HC];  // 32 KB
    int tid = threadIdx.x;
    {
        const float4* Wg4 = (const float4*)W1;
        float4* wl4 = (float4*)wl;
#pragma unroll
        for (int i = 0; i < 8; ++i) wl4[tid + i * 256] = Wg4[tid + i * 256];
    }
    __syncthreads();
    int lane = tid & 63;
    int row = blockIdx.x * 16 + (tid >> 6) * 4 + (lane >> 4);
    int c0 = (lane & 15) * 4;
    const float4* xr = (const float4*)(x + (size_t)row * IN_CH);
    float4 acc = make_float4(0.f, 0.f, 0.f, 0.f);
#pragma unroll 4
    for (int kq = 0; kq < IN_CH / 4; ++kq) {
        float4 xv = xr[kq];
        const float4* wrow = (const float4*)(wl + (kq * 4) * HC + c0);
        float4 w0 = wrow[0];
        float4 w1 = wrow[HC / 4];
        float4 w2 = wrow[2 * (HC / 4)];
        float4 w3 = wrow[3 * (HC / 4)];
        acc.x += xv.x * w0.x + xv.y * w1.x + xv.z * w2.x + xv.w * w3.x;
        acc.y += xv.x * w0.y + xv.y * w1.y + xv.z * w2.y + xv.w * w3.y;
        acc.z += xv.x * w0.z + xv.y * w1.z + xv.z * w2.z + xv.w * w3.z;
        acc.w += xv.x * w0.w + xv.y * w1.w + xv.z * w2.w + xv.w * w3.w;
    }
    ushort4 hb;
    hb.x = f2bf(acc.x); hb.y = f2bf(acc.y); hb.z = f2bf(acc.z); hb.w = f2bf(acc.w);
    *(ushort4*)(h1bf + (size_t)row * HC + c0) = hb;
    int head = (lane & 15) >> 1;
    int cl = c0 & 7;
    const float* as = aS + head * 8 + cl;
    const float* ad = aD + head * 8 + cl;
    float ps = acc.x * as[0] + acc.y * as[1] + acc.z * as[2] + acc.w * as[3];
    float pd = acc.x * ad[0] + acc.y * ad[1] + acc.z * ad[2] + acc.w * ad[3];
    ps += __shfl_xor(ps, 1, 64);
    pd += __shfl_xor(pd, 1, 64);
    if ((lane & 1) == 0) {
        asrc1[row * 8 + head] = ps;
        adst1[row * 8 + head] = pd;
    }
}

// ---------------- Layer 1 aggregation ----------------

__global__ __launch_bounds__(256) void k_agg1(const int* __restrict__ row_ptr,
                                              const int* __restrict__ csr,
                                              const float* __restrict__ asrc1,
                                              const float* __restrict__ adst1,
                                              const unsigned short* __restrict__ h1bf,
                                              const float* __restrict__ b1,
                                              float* __restrict__ hrelu) {
    int tid = threadIdx.x;
    int lane = tid & 63;
    int n = blockIdx.x * 4 + (tid >> 6);
    int slot = lane >> 3;  // 0..7 edge slot
    int hl = lane & 7;     // head
    float adst = adst1[n * 8 + hl];
    int beg = row_ptr[n], end = row_ptr[n + 1];
    int nit = (end - beg + 7) >> 3;
    float m = -3.0e38f, z = 0.f;
    float4 accA = make_float4(0.f, 0.f, 0.f, 0.f);
    float4 accB = make_float4(0.f, 0.f, 0.f, 0.f);
    const float4* h1v = (const float4*)h1bf;
    int j = beg + slot;
    int s_cur = (j < end) ? csr[j] : -1;
    for (int it = 0; it < nit; ++it) {
        int jn = j + 8;
        int s_nxt = (jn < end) ? csr[jn] : -1;
        if (s_cur >= 0) {
            float e = asrc1[s_cur * 8 + hl] + adst;
            e = (e > 0.f) ? e : 0.2f * e;
            float4 raw = h1v[(size_t)s_cur * 8 + hl];
            unsigned ux = __float_as_uint(raw.x), uy = __float_as_uint(raw.y);
            unsigned uz = __float_as_uint(raw.z), uw = __float_as_uint(raw.w);
            float v0 = __uint_as_float(ux << 16), v1 = __uint_as_float(ux & 0xffff0000u);
            float v2 = __uint_as_float(uy << 16), v3 = __uint_as_float(uy & 0xffff0000u);
            float v4 = __uint_as_float(uz << 16), v5 = __uint_as_float(uz & 0xffff0000u);
            float v6 = __uint_as_float(uw << 16), v7 = __uint_as_float(uw & 0xffff0000u);
            float mn = fmaxf(m, e);
            float rs = __expf(m - mn);
            float p = __expf(e - mn);
            m = mn;
            z = z * rs + p;
            accA.x = accA.x * rs + p * v0;
            accA.y = accA.y * rs + p * v1;
            accA.z = accA.z * rs + p * v2;
            accA.w = accA.w * rs + p * v3;
            accB.x = accB.x * rs + p * v4;
            accB.y = accB.y * rs + p * v5;
            accB.z = accB.z * rs + p * v6;
            accB.w = accB.w * rs + p * v7;
        }
        j = jn;
        s_cur = s_nxt;
    }
#pragma unroll
    for (int off = 8; off <= 32; off <<= 1) {
        float mo = __shfl_xor(m, off, 64);
        float zo = __shfl_xor(z, off, 64);
        float a0 = __shfl_xor(accA.x, off, 64);
        float a1 = __shfl_xor(accA.y, off, 64);
        float a2 = __shfl_xor(accA.z, off, 64);
        float a3 = __shfl_xor(accA.w, off, 64);
        float a4 = __shfl_xor(accB.x, off, 64);
        float a5 = __shfl_xor(accB.y, off, 64);
        float a6 = __shfl_xor(accB.z, off, 64);
        float a7 = __shfl_xor(accB.w, off, 64);
        float mn = fmaxf(m, mo);
        float rs = __expf(m - mn);
        float ro = __expf(mo - mn);
        m = mn;
        z = z * rs + zo * ro;
        accA.x = accA.x * rs + a0 * ro;
        accA.y = accA.y * rs + a1 * ro;
        accA.z = accA.z * rs + a2 * ro;
        accA.w = accA.w * rs + a3 * ro;
        accB.x = accB.x * rs + a4 * ro;
        accB.y = accB.y * rs + a5 * ro;
        accB.z = accB.z * rs + a6 * ro;
        accB.w = accB.w * rs + a7 * ro;
    }
    if (slot == 0) {
        float inv = 1.f / (z + 1e-16f);
        const float4* bv = (const float4*)(b1 + hl * 8);
        float4 b0 = bv[0], b1v = bv[1];
        float4 o0, o1;
        o0.x = fmaxf(accA.x * inv + b0.x, 0.f);
        o0.y = fmaxf(accA.y * inv + b0.y, 0.f);
        o0.z = fmaxf(accA.z * inv + b0.z, 0.f);
        o0.w = fmaxf(accA.w * inv + b0.w, 0.f);
        o1.x = fmaxf(accB.x * inv + b1v.x, 0.f);
        o1.y = fmaxf(accB.y * inv + b1v.y, 0.f);
        o1.z = fmaxf(accB.z * inv + b1v.z, 0.f);
        o1.w = fmaxf(accB.w * inv + b1v.w, 0.f);
        float4* op = (float4*)(hrelu + (size_t)n * HC + hl * 8);
        op[0] = o0;
        op[1] = o1;
    }
}

// ---------------- Layer 2: h2 = hrelu@W2, alpha2 ----------------

__global__ __launch_bounds__(256) void k_gemm2(const float* __restrict__ hrelu,
                                               const float* __restrict__ W2,
                                               const float* __restrict__ aS2,
                                               const float* __restrict__ aD2,
                                               float* __restrict__ h2,
                                               float* __restrict__ asrc2,
                                               float* __restrict__ adst2) {
    __shared__ float wl[HC * HID];  // 2 KB
    int tid = threadIdx.x;
    if (tid < 128) ((float4*)wl)[tid] = ((const float4*)W2)[tid];
    __syncthreads();
    int lane = tid & 63;
    int row = blockIdx.x * 32 + (tid >> 6) * 8 + (lane >> 3);
    int c = lane & 7;
    const float4* hr4 = (const float4*)(hrelu + (size_t)row * HC);
    float acc = 0.f;
#pragma unroll
    for (int kq = 0; kq < HC / 4; ++kq) {
        float4 hv = hr4[kq];
        acc += hv.x * wl[(kq * 4 + 0) * HID + c] + hv.y * wl[(kq * 4 + 1) * HID + c] +
               hv.z * wl[(kq * 4 + 2) * HID + c] + hv.w * wl[(kq * 4 + 3) * HID + c];
    }
    h2[(size_t)row * HID + c] = acc;
    float ps = acc * aS2[c];
    float pd = acc * aD2[c];
    ps += __shfl_xor(ps, 1, 64); ps += __shfl_xor(ps, 2, 64); ps += __shfl_xor(ps, 4, 64);
    pd += __shfl_xor(pd, 1, 64); pd += __shfl_xor(pd, 2, 64); pd += __shfl_xor(pd, 4, 64);
    if (c == 0) { asrc2[row] = ps; adst2[row] = pd; }
}

// ---------------- Layer 2 aggregation + classifier ----------------

__global__ __launch_bounds__(256) void k_agg2(const int* __restrict__ row_ptr,
                                              const int* __restrict__ csr,
                                              const float* __restrict__ asrc2,
                                              const float* __restrict__ adst2,
                                              const float* __restrict__ h2,
                                              const float* __restrict__ b2,
                                              const float* __restrict__ Wc,
                                              const float* __restrict__ bc,
                                              float* __restrict__ out) {
    int tid = threadIdx.x;
    int lane = tid & 63;
    int n = blockIdx.x * 4 + (tid >> 6);
    int slot = lane >> 3;
    int sl = lane & 7;
    float adst = adst2[n];
    int beg = row_ptr[n], end = row_ptr[n + 1];
    int nit = (end - beg + 7) >> 3;
    float m = -3.0e38f, z = 0.f, acc = 0.f;
    int j = beg + slot;
    int s_cur = (j < end) ? csr[j] : -1;
    for (int it = 0; it < nit; ++it) {
        int jn = j + 8;
        int s_nxt = (jn < end) ? csr[jn] : -1;
        if (s_cur >= 0) {
            float e = asrc2[s_cur] + adst;
            e = (e > 0.f) ? e : 0.2f * e;
            float hv = h2[(size_t)s_cur * HID + sl];
            float mn = fmaxf(m, e);
            float rs = __expf(m - mn);
            float p = __expf(e - mn);
            m = mn;
            z = z * rs + p;
            acc = acc * rs + p * hv;
        }
        j = jn;
        s_cur = s_nxt;
    }
#pragma unroll
    for (int off = 8; off <= 32; off <<= 1) {
        float mo = __shfl_xor(m, off, 64);
        float zo = __shfl_xor(z, off, 64);
        float ao = __shfl_xor(acc, off, 64);
        float mn = fmaxf(m, mo);
        float rs = __expf(m - mn);
        float ro = __expf(mo - mn);
        m = mn;
        z = z * rs + zo * ro;
        acc = acc * rs + ao * ro;
    }
    float emb = acc / (z + 1e-16f) + b2[sl];
    if (slot == 0) out[(size_t)n * HID + sl] = emb;
    float t0 = emb * Wc[sl * 2 + 0];
    float t1 = emb * Wc[sl * 2 + 1];
    t0 += __shfl_xor(t0, 1, 64); t0 += __shfl_xor(t0, 2, 64); t0 += __shfl_xor(t0, 4, 64);
    t1 += __shfl_xor(t1, 1, 64); t1 += __shfl_xor(t1, 2, 64); t1 += __shfl_xor(t1, 4, 64);
    if (lane == 0) {
        out[(size_t)NN * HID + n * 2 + 0] = t0 + bc[0];
        out[(size_t)NN * HID + n * 2 + 1] = t1 + bc[1];
    }
}

// ---------------- launch ----------------

extern "C" void kernel_launch(void* const* d_in, const int* in_sizes, int n_in,
                              void* d_out, int out_size, void* d_ws, size_t ws_size,
                              hipStream_t stream) {
    const float* x  = (const float*)d_in[0];
    const int*   ei = (const int*)d_in[1];
    const float* W1 = (const float*)d_in[2];
    const float* aS = (const float*)d_in[3];
    const float* aD = (const float*)d_in[4];
    const float* b1 = (const float*)d_in[5];
    const float* W2 = (const float*)d_in[6];
    const float* aS2 = (const float*)d_in[7];
    const float* aD2 = (const float*)d_in[8];
    const float* b2 = (const float*)d_in[9];
    const float* Wc = (const float*)d_in[10];
    const float* bc = (const float*)d_in[11];

    int E = in_sizes[1] / 2;
    int N = NN;
    int ET = E + N;
    int cpb = (ET + NBLK - 1) / NBLK;

    char* p = (char*)d_ws;
    auto alloc = [&](size_t bytes) -> char* {
        char* r = p;
        p += (bytes + 255) & ~(size_t)255;
        return r;
    };
    unsigned short* h1bf = (unsigned short*)alloc((size_t)N * HC * 2);  // 12.8 MB
    float* hrelu  = (float*)alloc((size_t)N * HC * 4);                  // 25.6 MB
    float* asrc1  = (float*)alloc((size_t)N * 8 * 4);
    float* adst1  = (float*)alloc((size_t)N * 8 * 4);
    float* h2     = (float*)alloc((size_t)N * HID * 4);
    float* asrc2  = (float*)alloc((size_t)N * 4);
    float* adst2  = (float*)alloc((size_t)N * 4);
    int*   row_ptr= (int*)alloc((size_t)(N + 1) * 4);
    int*   cnt    = (int*)alloc((size_t)NBUCK * NBLK * 4);  // 800 KB
    int*   btot   = (int*)alloc((size_t)NBUCK * 4);
    int*   bbase  = (int*)alloc((size_t)(NBUCK + 1) * 4);
    int*   csr    = (int*)alloc((size_t)ET * 4);            // 13.2 MB
    // pairs (26.4 MB) aliases h1bf+hrelu: consumed before k_gemm1 writes them
    int2*  pairs  = (int2*)h1bf;

    k_bincount<<<NBLK, 256, 0, stream>>>(ei, E, ET, cpb, cnt);
    k_colscan<<<NBUCK, 256, 0, stream>>>(cnt, btot);
    k_bucketbase<<<1, 256, 0, stream>>>(btot, bbase, row_ptr);
    k_binscatter<<<NBLK, 256, 0, stream>>>(ei, E, ET, cpb, cnt, bbase, pairs);
    k_bucketscatter<<<NBUCK, 256, 0, stream>>>(pairs, bbase, row_ptr, csr);

    k_gemm1<<<N / 16, 256, 0, stream>>>(x, W1, aS, aD, h1bf, asrc1, adst1);
    k_agg1<<<N / 4, 256, 0, stream>>>(row_ptr, csr, asrc1, adst1, h1bf, b1, hrelu);
    k_gemm2<<<N / 32, 256, 0, stream>>>(hrelu, W2, aS2, aD2, h2, asrc2, adst2);
    k_agg2<<<N / 4, 256, 0, stream>>>(row_ptr, csr, asrc2, adst2, h2, b2, Wc, bc,
                                      (float*)d_out);
}